// Round 4
// baseline (142.983 us; speedup 1.0000x reference)
//
#include <hip/hip_runtime.h>

// out[i, :] = weight[b[i], :]  (float32, Y_DIM=32), with out[0, :] = 0.
//
// Persistent grid-stride structure (same as round 3, which matched the
// harness fill kernel's shape), with two additions isolated for A/B:
//   1. NONTEMPORAL stores: the 128 MB output stream has zero reuse and
//      follows a 512 MB poison-fill that left L2 full of dirty lines.
//      Plain stores write-allocate -> evict those lines synchronously at
//      kernel start; nt bypasses allocation and keeps b/w4 resident.
//   2. Unroll 4 -> 8: longer independent store burst per iteration.
//
//   - 2048 blocks (8/CU, full occupancy), 256 threads.
//   - Weight table (64 x 128 B) staged once per block in LDS, padded to
//     9-float4 row stride (disjoint bank sets for 8 lane-groups).
//   - Grid-stride: per element one 4 B b-load (8 lanes share one cell ->
//     one 32 B segment/wave), one LDS read, one coalesced 16 B nt store.

typedef float f32x4 __attribute__((ext_vector_type(4)));

#define WROWS 64
#define WPAD  9   // LDS row stride in float4s (128 B data + 16 B pad)

__global__ __launch_bounds__(256) void batch_effect_gather_kernel(
        const int* __restrict__ b,
        const f32x4* __restrict__ w4,    // weight as [64, 8] float4
        f32x4* __restrict__ out4,        // output as [N, 8] float4
        int n_vec) {                     // N * 8 float4s
    __shared__ f32x4 sw[WROWS * WPAD];   // 9216 B

    // Stage weight table -> LDS (512 float4s, 2 per thread, coalesced).
    const int tid = threadIdx.x;
#pragma unroll
    for (int t = tid; t < WROWS * 8; t += 256)
        sw[(t >> 3) * WPAD + (t & 7)] = w4[t];
    __syncthreads();

    const int stride = gridDim.x * 256;
    int g = blockIdx.x * 256 + tid;

    // Main loop: 8 independent elements in flight per iteration.
    for (; g + 7 * stride < n_vec; g += 8 * stride) {
        int   c[8];
        int   bi[8];
        f32x4 v[8];
#pragma unroll
        for (int k = 0; k < 8; ++k) c[k] = g + k * stride;
#pragma unroll
        for (int k = 0; k < 8; ++k) bi[k] = b[c[k] >> 3];
#pragma unroll
        for (int k = 0; k < 8; ++k) v[k] = sw[bi[k] * WPAD + (c[k] & 7)];
        if (c[0] < 8) v[0] = (f32x4){0.f, 0.f, 0.f, 0.f};   // out[0,:] = 0
#pragma unroll
        for (int k = 0; k < 8; ++k)
            __builtin_nontemporal_store(v[k], &out4[c[k]]);
    }
    // Tail.
    for (; g < n_vec; g += stride) {
        f32x4 v = sw[b[g >> 3] * WPAD + (g & 7)];
        if (g < 8) v = (f32x4){0.f, 0.f, 0.f, 0.f};
        __builtin_nontemporal_store(v, &out4[g]);
    }
}

extern "C" void kernel_launch(void* const* d_in, const int* in_sizes, int n_in,
                              void* d_out, int out_size, void* d_ws, size_t ws_size,
                              hipStream_t stream) {
    const int*   b  = (const int*)d_in[0];      // [N, 1] int32
    const f32x4* w4 = (const f32x4*)d_in[1];    // [64, 32] f32 -> [64, 8] float4
    f32x4* out4 = (f32x4*)d_out;                // [N, 32] f32 -> [N, 8] float4

    int n_vec = in_sizes[0] * 8;                // N cells * 8 float4s/row
    int blocks = 2048;                          // 8 per CU, grid-stride
    batch_effect_gather_kernel<<<blocks, 256, 0, stream>>>(b, w4, out4, n_vec);
}